// Round 8
// baseline (701.625 us; speedup 1.0000x reference)
//
#include <hip/hip_runtime.h>
#include <math.h>

#define D 512
#define N_TOK 4096
#define NHEAD 16
#define DH 32
#define DEPTH 3
#define MLPD 2048
#define GENES 250
#define GH 64
#define GW 64

typedef __attribute__((ext_vector_type(8))) short short8;
typedef __attribute__((ext_vector_type(4))) float f32x4;
typedef unsigned short ushort_t;

#define AS1 __attribute__((address_space(1)))
#define AS3 __attribute__((address_space(3)))

#if defined(__has_builtin)
#if __has_builtin(__builtin_amdgcn_exp2f)
#define EXP2F(x) __builtin_amdgcn_exp2f(x)
#endif
#endif
#ifndef EXP2F
#define EXP2F(x) __expf(0.69314718056f * (x))
#endif

__device__ __forceinline__ unsigned short f2bf(float f) {
  unsigned int u = __float_as_uint(f);
  u += 0x7fffu + ((u >> 16) & 1u);
  return (unsigned short)(u >> 16);
}
__device__ __forceinline__ unsigned int bfpack(float a, float b) {
  return __builtin_amdgcn_perm(__float_as_uint(b), __float_as_uint(a), 0x07060302u);
}
__device__ __forceinline__ void gload_lds16(const ushort_t* g, ushort_t* l) {
  __builtin_amdgcn_global_load_lds(
      (const AS1 unsigned int*)g,
      (AS3 unsigned int*)(unsigned int)(unsigned long long)l, 16, 0, 0);
}
// s_waitcnt with vmcnt(N), expcnt ignored, lgkmcnt(0).
// imm encoding (gfx9): vm[3:0] | exp[6:4] | lgkm[11:8] | vm[15:14]
template <int N>
__device__ __forceinline__ void wait_vm_lgkm0() {
  if constexpr (N == 0) __builtin_amdgcn_s_waitcnt(0x070);
  else if constexpr (N == 2) __builtin_amdgcn_s_waitcnt(0x072);
  else __builtin_amdgcn_s_waitcnt(0x074);
}
// key permutation shared by the V^T store and the attention P-fragment
__device__ __forceinline__ int perm64(int m) {
  int mi = m >> 4, g = (m >> 2) & 3, r = m & 3;
  return ((mi & 1) << 5) | (g << 3) | ((mi >> 1) << 2) | r;
}

// ------------------------------- LayerNorm --------------------------------
__global__ __launch_bounds__(256) void ln_kernel(const float* __restrict__ x,
    const float* __restrict__ g, const float* __restrict__ b,
    float* __restrict__ yf, ushort_t* __restrict__ ybf) {
  int row = blockIdx.x;
  int t = threadIdx.x;
  const float* xr = x + (size_t)row * D;
  float v0 = xr[t], v1 = xr[t + 256];
  float s = v0 + v1;
  float sq = v0 * v0 + v1 * v1;
#pragma unroll
  for (int off = 32; off > 0; off >>= 1) {
    s += __shfl_down(s, off, 64);
    sq += __shfl_down(sq, off, 64);
  }
  __shared__ float s1[4], s2[4];
  int wid = t >> 6, lane = t & 63;
  if (lane == 0) { s1[wid] = s; s2[wid] = sq; }
  __syncthreads();
  float tot = s1[0] + s1[1] + s1[2] + s1[3];
  float totq = s2[0] + s2[1] + s2[2] + s2[3];
  float mean = tot * (1.0f / D);
  float var = totq * (1.0f / D) - mean * mean;
  float rs = rsqrtf(var + 1e-5f);
  float r0 = (v0 - mean) * rs * g[t] + b[t];
  float r1 = (v1 - mean) * rs * g[t + 256] + b[t + 256];
  if (yf) { yf[(size_t)row * D + t] = r0; yf[(size_t)row * D + t + 256] = r1; }
  if (ybf) {
    ybf[(size_t)row * D + t] = f2bf(r0);
    ybf[(size_t)row * D + t + 256] = f2bf(r1);
  }
}

// ---------------------------- bf16 MFMA GEMM -------------------------------
// C = act(A[M,Kfull] @ B[Npad,Kfull]^T + bias); tile TMxTN, BK=32.
// AITER-style pipeline: 3 LDS buffers, prefetch 2 iters ahead, raw s_barrier
// with manual s_waitcnt vmcnt(LD) lgkmcnt(0) (never vmcnt(0) mid-loop) so the
// 2-ahead stage stays in flight across the barrier.
// Split-K via blockIdx.z (K = per-split length, kbase = z*K).
// mode 0: fp32 store. mode 1: gelu -> Cbf. mode 2: qkv routing.
// mode 3: atomicAdd fp32 into C (+bias only on split 0).
template <int TM, int TN>
__global__ __launch_bounds__(256) void gemm_bf(
    const ushort_t* __restrict__ A, const ushort_t* __restrict__ B,
    const float* __restrict__ bias,
    float* __restrict__ C, ushort_t* __restrict__ Cbf,
    ushort_t* __restrict__ qO, ushort_t* __restrict__ kO, ushort_t* __restrict__ vO,
    int K, int lda, int ldc, int nstore, int mode) {
  constexpr int MI = TM / 32;
  constexpr int NI = TN / 32;
  constexpr int LD = (TM == 128 ? 2 : 1) + (TN == 128 ? 2 : 1);  // loads/stage/thread
  __shared__ ushort_t As[3][TM * 32];
  __shared__ ushort_t Bs[3][TN * 32];
  int t = threadIdx.x;
  int w = t >> 6, lane = t & 63;
  int g = lane >> 4, c = lane & 15;
  int bm = blockIdx.y * TM, bn = blockIdx.x * TN;
  int kbase = blockIdx.z * K;
  int wr = (w >> 1) * (TM / 2);
  int wc = (w & 1) * (TN / 2);

  const ushort_t* gA = A + (size_t)(bm + (t >> 2)) * lda + kbase + (t & 3) * 8;
  const ushort_t* gB = B + (size_t)(bn + (t >> 2)) * lda + kbase + (t & 3) * 8;

  auto stage = [&](int s, int koff) {
    gload_lds16(gA + koff, &As[s][t * 8]);
    if (TM == 128) gload_lds16(gA + koff + (size_t)64 * lda, &As[s][(t + 256) * 8]);
    gload_lds16(gB + koff, &Bs[s][t * 8]);
    if (TN == 128) gload_lds16(gB + koff + (size_t)64 * lda, &Bs[s][(t + 256) * 8]);
  };

  f32x4 acc[MI][NI] = {};
  const int niter = K / 32;
  stage(0, 0);
  stage(1, 32);
  wait_vm_lgkm0<LD>();                 // stage 0 drained; stage 1 in flight
  __builtin_amdgcn_s_barrier();
  for (int it = 0; it < niter; ++it) {
    int p = it % 3;
    if (it + 2 < niter) stage((it + 2) % 3, (it + 2) * 32);
    short8 af[MI], bfr[NI];
#pragma unroll
    for (int mi = 0; mi < MI; ++mi)
      af[mi] = *(const short8*)&As[p][(wr + mi * 16 + c) * 32 + g * 8];
#pragma unroll
    for (int ni = 0; ni < NI; ++ni)
      bfr[ni] = *(const short8*)&Bs[p][(wc + ni * 16 + c) * 32 + g * 8];
#pragma unroll
    for (int mi = 0; mi < MI; ++mi)
#pragma unroll
      for (int ni = 0; ni < NI; ++ni)
        acc[mi][ni] = __builtin_amdgcn_mfma_f32_16x16x32_bf16(
            af[mi], bfr[ni], acc[mi][ni], 0, 0, 0);
    if (it + 2 < niter) wait_vm_lgkm0<LD>();   // next stage drained, 2-ahead in flight
    else wait_vm_lgkm0<0>();
    __builtin_amdgcn_s_barrier();
  }

  const float qs_scale = 0.17677669529663688f * 1.4426950408889634f;
  if (mode == 2) {
#pragma unroll
    for (int ni = 0; ni < NI; ++ni) {
      int col = bn + wc + ni * 16 + c;
      float bv = bias[col];
      int which = col >> 9;
      int h = (col >> 5) & 15;
      int d = col & 31;
      size_t hb = (size_t)h * (N_TOK * DH);
#pragma unroll
      for (int mi = 0; mi < MI; ++mi) {
        int row0 = bm + wr + mi * 16 + g * 4;
        float v0 = acc[mi][ni][0] + bv;
        float v1 = acc[mi][ni][1] + bv;
        float v2 = acc[mi][ni][2] + bv;
        float v3 = acc[mi][ni][3] + bv;
        if (which == 0) {
          qO[hb + (size_t)(row0 + 0) * DH + d] = f2bf(v0 * qs_scale);
          qO[hb + (size_t)(row0 + 1) * DH + d] = f2bf(v1 * qs_scale);
          qO[hb + (size_t)(row0 + 2) * DH + d] = f2bf(v2 * qs_scale);
          qO[hb + (size_t)(row0 + 3) * DH + d] = f2bf(v3 * qs_scale);
        } else if (which == 1) {
          kO[hb + (size_t)(row0 + 0) * DH + d] = f2bf(v0);
          kO[hb + (size_t)(row0 + 1) * DH + d] = f2bf(v1);
          kO[hb + (size_t)(row0 + 2) * DH + d] = f2bf(v2);
          kO[hb + (size_t)(row0 + 3) * DH + d] = f2bf(v3);
        } else {
          int m = row0 & 63;
          int mi_l = m >> 4, g_l = (m >> 2) & 3;
          int nb = ((mi_l & 1) << 5) | (g_l << 3) | ((mi_l >> 1) << 2);
          uint2 pk;
          pk.x = (unsigned)f2bf(v0) | ((unsigned)f2bf(v1) << 16);
          pk.y = (unsigned)f2bf(v2) | ((unsigned)f2bf(v3) << 16);
          *(uint2*)(vO + hb + (size_t)d * N_TOK + (row0 & ~63) + nb) = pk;
        }
      }
    }
    return;
  }
  bool addb = (blockIdx.z == 0);
#pragma unroll
  for (int ni = 0; ni < NI; ++ni) {
    int col = bn + wc + ni * 16 + c;
    float bv = bias[col];
    bool cok = col < nstore;
#pragma unroll
    for (int mi = 0; mi < MI; ++mi) {
      int row0 = bm + wr + mi * 16 + g * 4;
#pragma unroll
      for (int reg = 0; reg < 4; ++reg) {
        int row = row0 + reg;
        float v = acc[mi][ni][reg];
        if (mode == 3) {
          if (cok) atomicAdd(&C[(size_t)row * ldc + col], v + (addb ? bv : 0.f));
        } else if (mode == 0) {
          if (cok) C[(size_t)row * ldc + col] = v + bv;
        } else {
          v += bv;
          v = 0.5f * v * (1.0f + erff(v * 0.70710678118654752f));
          Cbf[(size_t)row * ldc + col] = f2bf(v);
        }
      }
    }
  }
}

// --------------------------- MFMA flash attention --------------------------
// grid (N_TOK/128, NHEAD), 256 thr. Wave owns 32 queries. Double-buffered LDS
// staging of K (64x32, stride 40) and V^T (32x64, stride 72): one barrier per
// tile (write next tile into parity buffer during compute). P stays in
// registers (S^T C-frag == B-frag under perm64); l on the MFMA pipe.
#define KST 40
#define VTST 72
#define NTILE (N_TOK / 64)

__global__ __launch_bounds__(256) void attn_mfma(
    const ushort_t* __restrict__ qb, const ushort_t* __restrict__ kb,
    const ushort_t* __restrict__ vtb, ushort_t* __restrict__ ao) {
  __shared__ ushort_t Ks[2][64 * KST];
  __shared__ ushort_t Vts[2][32 * VTST];
  int qt = blockIdx.x, head = blockIdx.y;
  int t = threadIdx.x;
  int w = t >> 6, lane = t & 63;
  int g = lane >> 4, c = lane & 15;
  const size_t hbase = (size_t)head * (N_TOK * DH);
  int q0 = qt * 128 + w * 32;

  short8 qf[2];
  qf[0] = *(const short8*)(qb + hbase + (size_t)(q0 + c) * DH + g * 8);
  qf[1] = *(const short8*)(qb + hbase + (size_t)(q0 + 16 + c) * DH + g * 8);

  short8 ones;
#pragma unroll
  for (int i = 0; i < 8; ++i) ones[i] = (short)0x3F80;

  f32x4 o[2][2] = {};
  f32x4 lf[2] = {};
  const f32x4 zf = {0.f, 0.f, 0.f, 0.f};

  const ushort_t* kg = kb + hbase + (size_t)(t >> 2) * DH + (t & 3) * 8;
  const ushort_t* vg = vtb + hbase + (size_t)(t >> 3) * N_TOK + (t & 7) * 8;
  const int kwo = (t >> 2) * KST + (t & 3) * 8;
  const int vwo = (t >> 3) * VTST + (t & 7) * 8;

  short8 kreg = *(const short8*)kg;
  short8 vreg = *(const short8*)vg;
  *(short8*)&Ks[0][kwo] = kreg;
  *(short8*)&Vts[0][vwo] = vreg;
  kreg = *(const short8*)(kg + (size_t)64 * DH);
  vreg = *(const short8*)(vg + 64);
  __syncthreads();

  typedef union { short8 s8; unsigned int u32[4]; } pk_t;

  for (int tile = 0; tile < NTILE; ++tile) {
    int p = tile & 1;
    if (tile + 1 < NTILE) {
      *(short8*)&Ks[p ^ 1][kwo] = kreg;
      *(short8*)&Vts[p ^ 1][vwo] = vreg;
      if (tile + 2 < NTILE) {
        kreg = *(const short8*)(kg + (size_t)(tile + 2) * 64 * DH);
        vreg = *(const short8*)(vg + (tile + 2) * 64);
      }
    }

    short8 kf[4];
#pragma unroll
    for (int mi = 0; mi < 4; ++mi)
      kf[mi] = *(const short8*)&Ks[p][(mi * 16 + c) * KST + g * 8];
    short8 vf[2][2];
#pragma unroll
    for (int half = 0; half < 2; ++half)
#pragma unroll
      for (int ch = 0; ch < 2; ++ch)
        vf[half][ch] = *(const short8*)&Vts[p][(half * 16 + c) * VTST + ch * 32 + g * 8];

    short8 pf[2][2];
#pragma unroll
    for (int qs = 0; qs < 2; ++qs) {
      f32x4 sp[4];
#pragma unroll
      for (int mi = 0; mi < 4; ++mi)
        sp[mi] = __builtin_amdgcn_mfma_f32_16x16x32_bf16(kf[mi], qf[qs], zf, 0, 0, 0);
      float pr[4][4];
#pragma unroll
      for (int mi = 0; mi < 4; ++mi)
#pragma unroll
        for (int r = 0; r < 4; ++r) pr[mi][r] = EXP2F(sp[mi][r]);
      pk_t p0, p1;
      p0.u32[0] = bfpack(pr[0][0], pr[0][1]);
      p0.u32[1] = bfpack(pr[0][2], pr[0][3]);
      p0.u32[2] = bfpack(pr[2][0], pr[2][1]);
      p0.u32[3] = bfpack(pr[2][2], pr[2][3]);
      p1.u32[0] = bfpack(pr[1][0], pr[1][1]);
      p1.u32[1] = bfpack(pr[1][2], pr[1][3]);
      p1.u32[2] = bfpack(pr[3][0], pr[3][1]);
      p1.u32[3] = bfpack(pr[3][2], pr[3][3]);
      pf[qs][0] = p0.s8;
      pf[qs][1] = p1.s8;
    }

#pragma unroll
    for (int qs = 0; qs < 2; ++qs) {
#pragma unroll
      for (int ch = 0; ch < 2; ++ch) {
        lf[qs] = __builtin_amdgcn_mfma_f32_16x16x32_bf16(ones, pf[qs][ch], lf[qs], 0, 0, 0);
#pragma unroll
        for (int half = 0; half < 2; ++half)
          o[qs][half] = __builtin_amdgcn_mfma_f32_16x16x32_bf16(
              vf[half][ch], pf[qs][ch], o[qs][half], 0, 0, 0);
      }
    }
    __syncthreads();
  }

#pragma unroll
  for (int qs = 0; qs < 2; ++qs) {
    float inv = 1.0f / lf[qs][0];
    int q = q0 + qs * 16 + c;
    ushort_t* op = ao + (size_t)q * D + head * DH;
#pragma unroll
    for (int half = 0; half < 2; ++half)
#pragma unroll
      for (int reg = 0; reg < 4; ++reg)
        op[half * 16 + g * 4 + reg] = f2bf(o[qs][half][reg] * inv);
  }
}

// ------------------------- depthwise conv + next-LN ------------------------
__global__ void scatter_kernel(const int* __restrict__ coords,
                               int* __restrict__ pos2tok) {
  int n = blockIdx.x * 256 + threadIdx.x;
  if (n < N_TOK) pos2tok[coords[2 * n] * GW + coords[2 * n + 1]] = n;
}

__global__ __launch_bounds__(256) void conv_ln_kernel(
    const float* __restrict__ xin, float* __restrict__ xout,
    const float* __restrict__ ck, const float* __restrict__ cb,
    const int* __restrict__ pos2tok, const int* __restrict__ coords,
    const float* __restrict__ g, const float* __restrict__ b,
    float* __restrict__ yf, ushort_t* __restrict__ ybf) {
  int n = blockIdx.x, t = threadIdx.x;
  __shared__ int nb[9];
  if (t < 9) {
    int r = coords[2 * n], c = coords[2 * n + 1];
    int dy = t / 3 - 1, dx = t % 3 - 1;
    int rr = r + dy, cc = c + dx;
    nb[t] = (rr >= 0 && rr < GH && cc >= 0 && cc < GW) ? pos2tok[rr * GW + cc] : -1;
  }
  __syncthreads();
  float v[2];
#pragma unroll
  for (int j = 0; j < 2; ++j) {
    int ch = t + j * 256;
    float s = cb[ch];
#pragma unroll
    for (int tap = 0; tap < 9; ++tap) {
      int tok = nb[tap];
      if (tok >= 0) s = fmaf(ck[ch * 9 + tap], xin[(size_t)tok * D + ch], s);
    }
    v[j] = xin[(size_t)n * D + ch] + s;
    xout[(size_t)n * D + ch] = v[j];
  }
  float s = v[0] + v[1];
  float sq = v[0] * v[0] + v[1] * v[1];
#pragma unroll
  for (int off = 32; off > 0; off >>= 1) {
    s += __shfl_down(s, off, 64);
    sq += __shfl_down(sq, off, 64);
  }
  __shared__ float s1[4], s2[4];
  int wid = t >> 6, lane = t & 63;
  if (lane == 0) { s1[wid] = s; s2[wid] = sq; }
  __syncthreads();
  float tot = s1[0] + s1[1] + s1[2] + s1[3];
  float totq = s2[0] + s2[1] + s2[2] + s2[3];
  float mean = tot * (1.0f / D);
  float var = totq * (1.0f / D) - mean * mean;
  float rs = rsqrtf(var + 1e-5f);
  float r0 = (v[0] - mean) * rs * g[t] + b[t];
  float r1 = (v[1] - mean) * rs * g[t + 256] + b[t + 256];
  if (yf) { yf[(size_t)n * D + t] = r0; yf[(size_t)n * D + t + 256] = r1; }
  ybf[(size_t)n * D + t] = f2bf(r0);
  ybf[(size_t)n * D + t + 256] = f2bf(r1);
}

// ------------------------ weight cast (fp32->bf16, pad) --------------------
__global__ __launch_bounds__(256) void castw(const float* __restrict__ src,
    ushort_t* __restrict__ dst, int n_src, int n_dst) {
  int i = (blockIdx.x * 256 + threadIdx.x) * 4;
  if (i >= n_dst) return;
  unsigned long long pk = 0;
#pragma unroll
  for (int j = 0; j < 4; ++j) {
    float v = (i + j < n_src) ? src[i + j] : 0.f;
    pk |= ((unsigned long long)f2bf(v)) << (16 * j);
  }
  *(unsigned long long*)(dst + i) = pk;
}

__global__ void pad_bias(const float* __restrict__ src, float* __restrict__ dst) {
  int i = threadIdx.x;
  dst[i] = (i < GENES) ? src[i] : 0.f;
}

// ------------------------------- launch ------------------------------------
extern "C" void kernel_launch(void* const* d_in, const int* in_sizes, int n_in,
                              void* d_out, int out_size, void* d_ws, size_t ws_size,
                              hipStream_t stream) {
  const float* gf     = (const float*)d_in[0];
  const int*   coords = (const int*)d_in[1];
  const float* ln1_g  = (const float*)d_in[4];
  const float* ln1_b  = (const float*)d_in[5];
  const float* wqkv   = (const float*)d_in[6];
  const float* bqkv   = (const float*)d_in[7];
  const float* wo     = (const float*)d_in[8];
  const float* bo     = (const float*)d_in[9];
  const float* ln2_g  = (const float*)d_in[10];
  const float* ln2_b  = (const float*)d_in[11];
  const float* w1     = (const float*)d_in[12];
  const float* b1     = (const float*)d_in[13];
  const float* w2     = (const float*)d_in[14];
  const float* b2     = (const float*)d_in[15];
  const float* ck     = (const float*)d_in[16];
  const float* cb     = (const float*)d_in[17];
  const float* lnf_g  = (const float*)d_in[18];
  const float* lnf_b  = (const float*)d_in[19];
  const float* wp     = (const float*)d_in[20];
  const float* bp     = (const float*)d_in[21];
  float* out = (float*)d_out;

  const size_t ND = (size_t)N_TOK * D;
  float* xb0 = (float*)d_ws;
  float* xb1 = xb0 + ND;
  ushort_t* xn_bf  = (ushort_t*)(xb1 + ND);      // ND
  ushort_t* ao_bf  = xn_bf + ND;                 // ND
  ushort_t* out_bf = ao_bf + ND;                 // ND
  ushort_t* shared = out_bf + ND;                // max(3*ND, N*MLPD)
  ushort_t* qb   = shared;
  ushort_t* kbuf = qb + ND;
  ushort_t* vtb  = kbuf + ND;
  ushort_t* h_bf = shared;                       // aliases qkv bufs (disjoint lifetime)
  ushort_t* wqkv_bf = shared + (size_t)N_TOK * MLPD;
  ushort_t* wo_bf = wqkv_bf + DEPTH * 3 * D * D;
  ushort_t* w1_bf = wo_bf + DEPTH * D * D;
  ushort_t* w2_bf = w1_bf + DEPTH * MLPD * D;
  ushort_t* wp_bf = w2_bf + DEPTH * D * MLPD;
  float* bp_pad = (float*)(wp_bf + 256 * D);
  int* pos2tok = (int*)(bp_pad + 256);

  hipMemcpyAsync(xb0, gf, ND * sizeof(float), hipMemcpyDeviceToDevice, stream);
  hipMemsetAsync(pos2tok, 0xFF, GH * GW * sizeof(int), stream);
  // head gemm uses atomicAdd -> zero the pred region up front
  hipMemsetAsync(out + ND, 0, (size_t)N_TOK * GENES * sizeof(float), stream);
  scatter_kernel<<<(N_TOK + 255) / 256, 256, 0, stream>>>(coords, pos2tok);

  int nw;
  nw = DEPTH * 3 * D * D;  castw<<<(nw / 4 + 255) / 256, 256, 0, stream>>>(wqkv, wqkv_bf, nw, nw);
  nw = DEPTH * D * D;      castw<<<(nw / 4 + 255) / 256, 256, 0, stream>>>(wo, wo_bf, nw, nw);
  nw = DEPTH * MLPD * D;   castw<<<(nw / 4 + 255) / 256, 256, 0, stream>>>(w1, w1_bf, nw, nw);
  nw = DEPTH * D * MLPD;   castw<<<(nw / 4 + 255) / 256, 256, 0, stream>>>(w2, w2_bf, nw, nw);
  castw<<<(256 * D / 4 + 255) / 256, 256, 0, stream>>>(wp, wp_bf, GENES * D, 256 * D);
  pad_bias<<<1, 256, 0, stream>>>(bp, bp_pad);

  // ln1 of layer 0 (subsequent ln1/lnf are fused into conv_ln)
  ln_kernel<<<N_TOK, 256, 0, stream>>>(xb0, ln1_g, ln1_b, nullptr, xn_bf);

  float* x  = xb0;
  float* xo = xb1;
  for (int i = 0; i < DEPTH; ++i) {
    gemm_bf<128, 128><<<dim3(12, 32, 1), 256, 0, stream>>>(
        xn_bf, wqkv_bf + (size_t)i * 3 * D * D, bqkv + (size_t)i * 3 * D,
        nullptr, nullptr, qb, kbuf, vtb, D, D, 0, 3 * D, 2);
    attn_mfma<<<dim3(N_TOK / 128, NHEAD), 256, 0, stream>>>(qb, kbuf, vtb, ao_bf);
    // wo: split-K=2, atomicAdd into x (x already holds the residual)
    gemm_bf<64, 64><<<dim3(8, 64, 2), 256, 0, stream>>>(
        ao_bf, wo_bf + (size_t)i * D * D, bo + (size_t)i * D,
        x, nullptr, nullptr, nullptr, nullptr, D / 2, D, D, D, 3);
    ln_kernel<<<N_TOK, 256, 0, stream>>>(x, ln2_g + i * D, ln2_b + i * D, nullptr, xn_bf);
    gemm_bf<128, 128><<<dim3(16, 32, 1), 256, 0, stream>>>(
        xn_bf, w1_bf + (size_t)i * MLPD * D, b1 + (size_t)i * MLPD,
        nullptr, h_bf, nullptr, nullptr, nullptr, D, D, MLPD, MLPD, 1);
    // w2: split-K=4, atomicAdd into x
    gemm_bf<64, 64><<<dim3(8, 64, 4), 256, 0, stream>>>(
        h_bf, w2_bf + (size_t)i * D * MLPD, b2 + (size_t)i * D,
        x, nullptr, nullptr, nullptr, nullptr, MLPD / 4, MLPD, D, D, 3);
    if (i < DEPTH - 1) {
      conv_ln_kernel<<<N_TOK, 256, 0, stream>>>(
          x, xo, ck + (size_t)i * D * 9, cb + (size_t)i * D, pos2tok, coords,
          ln1_g + (i + 1) * D, ln1_b + (i + 1) * D, nullptr, xn_bf);
    } else {
      conv_ln_kernel<<<N_TOK, 256, 0, stream>>>(
          x, xo, ck + (size_t)i * D * 9, cb + (size_t)i * D, pos2tok, coords,
          lnf_g, lnf_b, out, out_bf);
    }
    float* tmp = x; x = xo; xo = tmp;
  }
  // head: split-K=2, atomicAdd into zeroed pred region
  gemm_bf<64, 64><<<dim3(4, 64, 2), 256, 0, stream>>>(
      out_bf, wp_bf, bp_pad, out + ND, nullptr, nullptr, nullptr, nullptr,
      D / 2, D, GENES, GENES, 3);
}

// Round 9
// 633.238 us; speedup vs baseline: 1.1080x; 1.1080x over previous
//
#include <hip/hip_runtime.h>
#include <math.h>

#define D 512
#define N_TOK 4096
#define NHEAD 16
#define DH 32
#define DEPTH 3
#define MLPD 2048
#define GENES 250
#define GH 64
#define GW 64

typedef __attribute__((ext_vector_type(8))) short short8;
typedef __attribute__((ext_vector_type(4))) float f32x4;
typedef unsigned short ushort_t;

#define AS1 __attribute__((address_space(1)))
#define AS3 __attribute__((address_space(3)))

#if defined(__has_builtin)
#if __has_builtin(__builtin_amdgcn_exp2f)
#define EXP2F(x) __builtin_amdgcn_exp2f(x)
#endif
#endif
#ifndef EXP2F
#define EXP2F(x) __expf(0.69314718056f * (x))
#endif

__device__ __forceinline__ unsigned short f2bf(float f) {
  unsigned int u = __float_as_uint(f);
  u += 0x7fffu + ((u >> 16) & 1u);
  return (unsigned short)(u >> 16);
}
__device__ __forceinline__ unsigned int bfpack(float a, float b) {
  return __builtin_amdgcn_perm(__float_as_uint(b), __float_as_uint(a), 0x07060302u);
}
__device__ __forceinline__ void gload_lds16(const ushort_t* g, ushort_t* l) {
  __builtin_amdgcn_global_load_lds(
      (const AS1 unsigned int*)g,
      (AS3 unsigned int*)(unsigned int)(unsigned long long)l, 16, 0, 0);
}
// key permutation shared by the V^T store and the attention P-fragment
__device__ __forceinline__ int perm64(int m) {
  int mi = m >> 4, g = (m >> 2) & 3, r = m & 3;
  return ((mi & 1) << 5) | (g << 3) | ((mi >> 1) << 2) | r;
}

// ------------------------------- LayerNorm --------------------------------
__global__ __launch_bounds__(256) void ln_kernel(const float* __restrict__ x,
    const float* __restrict__ g, const float* __restrict__ b,
    float* __restrict__ yf, ushort_t* __restrict__ ybf) {
  int row = blockIdx.x;
  int t = threadIdx.x;
  const float* xr = x + (size_t)row * D;
  float v0 = xr[t], v1 = xr[t + 256];
  float s = v0 + v1;
  float sq = v0 * v0 + v1 * v1;
#pragma unroll
  for (int off = 32; off > 0; off >>= 1) {
    s += __shfl_down(s, off, 64);
    sq += __shfl_down(sq, off, 64);
  }
  __shared__ float s1[4], s2[4];
  int wid = t >> 6, lane = t & 63;
  if (lane == 0) { s1[wid] = s; s2[wid] = sq; }
  __syncthreads();
  float tot = s1[0] + s1[1] + s1[2] + s1[3];
  float totq = s2[0] + s2[1] + s2[2] + s2[3];
  float mean = tot * (1.0f / D);
  float var = totq * (1.0f / D) - mean * mean;
  float rs = rsqrtf(var + 1e-5f);
  float r0 = (v0 - mean) * rs * g[t] + b[t];
  float r1 = (v1 - mean) * rs * g[t + 256] + b[t + 256];
  if (yf) { yf[(size_t)row * D + t] = r0; yf[(size_t)row * D + t + 256] = r1; }
  if (ybf) {
    ybf[(size_t)row * D + t] = f2bf(r0);
    ybf[(size_t)row * D + t + 256] = f2bf(r1);
  }
}

// ---------------------------- bf16 MFMA GEMM -------------------------------
// R7 structure (best measured): tile TMxTN, BK=32*NKH, double-buffered LDS,
// prefetch of iter k+1 issued right after the barrier releasing the buffer,
// before iter k's compute. One __syncthreads per iter.
// mode 0: fp32 C (+res). mode 1: gelu -> Cbf. mode 2: qkv routing.
template <int TM, int TN, int NKH>
__global__ __launch_bounds__(256) void gemm_bf(
    const ushort_t* __restrict__ A, const ushort_t* __restrict__ B,
    const float* __restrict__ bias, const float* __restrict__ res,
    float* __restrict__ C, ushort_t* __restrict__ Cbf,
    ushort_t* __restrict__ qO, ushort_t* __restrict__ kO, ushort_t* __restrict__ vO,
    int K, int ldc, int nstore, int mode) {
  constexpr int MI = TM / 32;
  constexpr int NI = TN / 32;
  __shared__ ushort_t As[2][NKH][TM * 32];
  __shared__ ushort_t Bs[2][NKH][TN * 32];
  int t = threadIdx.x;
  int w = t >> 6, lane = t & 63;
  int g = lane >> 4, c = lane & 15;
  int bm = blockIdx.y * TM, bn = blockIdx.x * TN;
  int wr = (w >> 1) * (TM / 2);
  int wc = (w & 1) * (TN / 2);

  const ushort_t* gA = A + (size_t)(bm + (t >> 2)) * K + (t & 3) * 8;
  const ushort_t* gB = B + (size_t)(bn + (t >> 2)) * K + (t & 3) * 8;

  auto stage = [&](int p, int koff) {
#pragma unroll
    for (int h = 0; h < NKH; ++h) {
      gload_lds16(gA + koff + h * 32, &As[p][h][t * 8]);
      if (TM == 128)
        gload_lds16(gA + koff + h * 32 + (size_t)64 * K, &As[p][h][(t + 256) * 8]);
      gload_lds16(gB + koff + h * 32, &Bs[p][h][t * 8]);
      if (TN == 128)
        gload_lds16(gB + koff + h * 32 + (size_t)64 * K, &Bs[p][h][(t + 256) * 8]);
    }
  };

  f32x4 acc[MI][NI] = {};

  const int niter = K / (32 * NKH);
  stage(0, 0);
  __syncthreads();
  for (int it = 0; it < niter; ++it) {
    int p = it & 1;
    if (it + 1 < niter) stage(p ^ 1, (it + 1) * 32 * NKH);  // prefetch overlaps compute
#pragma unroll
    for (int kh = 0; kh < NKH; ++kh) {
      short8 af[MI], bfr[NI];
#pragma unroll
      for (int mi = 0; mi < MI; ++mi)
        af[mi] = *(const short8*)&As[p][kh][(wr + mi * 16 + c) * 32 + g * 8];
#pragma unroll
      for (int ni = 0; ni < NI; ++ni)
        bfr[ni] = *(const short8*)&Bs[p][kh][(wc + ni * 16 + c) * 32 + g * 8];
#pragma unroll
      for (int mi = 0; mi < MI; ++mi)
#pragma unroll
        for (int ni = 0; ni < NI; ++ni)
          acc[mi][ni] = __builtin_amdgcn_mfma_f32_16x16x32_bf16(
              af[mi], bfr[ni], acc[mi][ni], 0, 0, 0);
    }
    __syncthreads();
  }

  const float qs_scale = 0.17677669529663688f * 1.4426950408889634f;
  if (mode == 2) {
#pragma unroll
    for (int ni = 0; ni < NI; ++ni) {
      int col = bn + wc + ni * 16 + c;
      float bv = bias[col];
      int which = col >> 9;
      int h = (col >> 5) & 15;
      int d = col & 31;
      size_t hb = (size_t)h * (N_TOK * DH);
#pragma unroll
      for (int mi = 0; mi < MI; ++mi) {
        int row0 = bm + wr + mi * 16 + g * 4;
        float v0 = acc[mi][ni][0] + bv;
        float v1 = acc[mi][ni][1] + bv;
        float v2 = acc[mi][ni][2] + bv;
        float v3 = acc[mi][ni][3] + bv;
        if (which == 0) {
          qO[hb + (size_t)(row0 + 0) * DH + d] = f2bf(v0 * qs_scale);
          qO[hb + (size_t)(row0 + 1) * DH + d] = f2bf(v1 * qs_scale);
          qO[hb + (size_t)(row0 + 2) * DH + d] = f2bf(v2 * qs_scale);
          qO[hb + (size_t)(row0 + 3) * DH + d] = f2bf(v3 * qs_scale);
        } else if (which == 1) {
          kO[hb + (size_t)(row0 + 0) * DH + d] = f2bf(v0);
          kO[hb + (size_t)(row0 + 1) * DH + d] = f2bf(v1);
          kO[hb + (size_t)(row0 + 2) * DH + d] = f2bf(v2);
          kO[hb + (size_t)(row0 + 3) * DH + d] = f2bf(v3);
        } else {
          int m = row0 & 63;
          int mi_l = m >> 4, g_l = (m >> 2) & 3;
          int nb = ((mi_l & 1) << 5) | (g_l << 3) | ((mi_l >> 1) << 2);
          uint2 pk;
          pk.x = (unsigned)f2bf(v0) | ((unsigned)f2bf(v1) << 16);
          pk.y = (unsigned)f2bf(v2) | ((unsigned)f2bf(v3) << 16);
          *(uint2*)(vO + hb + (size_t)d * N_TOK + (row0 & ~63) + nb) = pk;
        }
      }
    }
    return;
  }
#pragma unroll
  for (int ni = 0; ni < NI; ++ni) {
    int col = bn + wc + ni * 16 + c;
    float bv = bias[col];
    bool cok = col < nstore;
#pragma unroll
    for (int mi = 0; mi < MI; ++mi) {
      int row0 = bm + wr + mi * 16 + g * 4;
#pragma unroll
      for (int reg = 0; reg < 4; ++reg) {
        int row = row0 + reg;
        float v = acc[mi][ni][reg] + bv;
        if (mode == 0) {
          size_t idx = (size_t)row * ldc + col;
          if (cok) {
            if (res) v += res[idx];
            C[idx] = v;
          }
        } else {
          v = 0.5f * v * (1.0f + erff(v * 0.70710678118654752f));
          Cbf[(size_t)row * ldc + col] = f2bf(v);
        }
      }
    }
  }
}

// --------------------------- MFMA flash attention --------------------------
// KV-split: grid (N_TOK/128, NHEAD, 2); block z handles key tiles
// [z*32, z*32+32). R7's single-buffer staging + reg prefetch. Outputs
// UNNORMALIZED o (fp32) and l per (part, head, q); no-max softmax makes the
// cross-part merge a plain weighted sum. 1024 blocks -> 4 blocks/CU ->
// 16 waves/CU (vs 8) to overlap the ds_read->MFMA->exp->pack chain.
#define KST 40   // Ks row stride (ushorts)
#define VTST 72  // Vts row stride (ushorts)

__global__ __launch_bounds__(256) void attn_mfma(
    const ushort_t* __restrict__ qb, const ushort_t* __restrict__ kb,
    const ushort_t* __restrict__ vtb, float* __restrict__ po,
    float* __restrict__ lp) {
  __shared__ ushort_t Ks[64 * KST];
  __shared__ ushort_t Vts[32 * VTST];
  int qt = blockIdx.x, head = blockIdx.y, z = blockIdx.z;
  int t = threadIdx.x;
  int w = t >> 6, lane = t & 63;
  int g = lane >> 4, c = lane & 15;
  const size_t hbase = (size_t)head * (N_TOK * DH);
  int q0 = qt * 128 + w * 32;

  short8 qf[2];
  qf[0] = *(const short8*)(qb + hbase + (size_t)(q0 + c) * DH + g * 8);
  qf[1] = *(const short8*)(qb + hbase + (size_t)(q0 + 16 + c) * DH + g * 8);

  short8 ones;
#pragma unroll
  for (int i = 0; i < 8; ++i) ones[i] = (short)0x3F80;

  f32x4 o[2][2] = {};
  f32x4 lf[2] = {};
  const f32x4 zf = {0.f, 0.f, 0.f, 0.f};

  const int kv0 = z * (N_TOK / 2);      // first key row of this part
  const ushort_t* kg = kb + hbase + (size_t)(kv0 + (t >> 2)) * DH + (t & 3) * 8;
  const ushort_t* vg = vtb + hbase + (size_t)(t >> 3) * N_TOK + kv0 + (t & 7) * 8;
  ushort_t* kw = &Ks[(t >> 2) * KST + (t & 3) * 8];
  ushort_t* vw = &Vts[(t >> 3) * VTST + (t & 7) * 8];

  short8 kreg = *(const short8*)kg;
  short8 vreg = *(const short8*)vg;

  typedef union { short8 s8; unsigned int u32[4]; } pk_t;

  const int ntile = N_TOK / 2 / 64;     // 32 tiles per part
  for (int tile = 0; tile < ntile; ++tile) {
    __syncthreads();
    *(short8*)kw = kreg;
    *(short8*)vw = vreg;
    __syncthreads();
    if (tile + 1 < ntile) {
      kreg = *(const short8*)(kg + (size_t)(tile + 1) * 64 * DH);
      vreg = *(const short8*)(vg + (tile + 1) * 64);
    }

    short8 kf[4];
#pragma unroll
    for (int mi = 0; mi < 4; ++mi)
      kf[mi] = *(const short8*)&Ks[(mi * 16 + c) * KST + g * 8];
    short8 vf[2][2];
#pragma unroll
    for (int half = 0; half < 2; ++half)
#pragma unroll
      for (int ch = 0; ch < 2; ++ch)
        vf[half][ch] = *(const short8*)&Vts[(half * 16 + c) * VTST + ch * 32 + g * 8];

    short8 pf[2][2];
#pragma unroll
    for (int qs = 0; qs < 2; ++qs) {
      f32x4 sp[4];
#pragma unroll
      for (int mi = 0; mi < 4; ++mi)
        sp[mi] = __builtin_amdgcn_mfma_f32_16x16x32_bf16(kf[mi], qf[qs], zf, 0, 0, 0);
      float pr[4][4];
#pragma unroll
      for (int mi = 0; mi < 4; ++mi)
#pragma unroll
        for (int r = 0; r < 4; ++r) pr[mi][r] = EXP2F(sp[mi][r]);
      pk_t p0, p1;
      p0.u32[0] = bfpack(pr[0][0], pr[0][1]);
      p0.u32[1] = bfpack(pr[0][2], pr[0][3]);
      p0.u32[2] = bfpack(pr[2][0], pr[2][1]);
      p0.u32[3] = bfpack(pr[2][2], pr[2][3]);
      p1.u32[0] = bfpack(pr[1][0], pr[1][1]);
      p1.u32[1] = bfpack(pr[1][2], pr[1][3]);
      p1.u32[2] = bfpack(pr[3][0], pr[3][1]);
      p1.u32[3] = bfpack(pr[3][2], pr[3][3]);
      pf[qs][0] = p0.s8;
      pf[qs][1] = p1.s8;
    }

#pragma unroll
    for (int qs = 0; qs < 2; ++qs) {
#pragma unroll
      for (int ch = 0; ch < 2; ++ch) {
        lf[qs] = __builtin_amdgcn_mfma_f32_16x16x32_bf16(ones, pf[qs][ch], lf[qs], 0, 0, 0);
#pragma unroll
        for (int half = 0; half < 2; ++half)
          o[qs][half] = __builtin_amdgcn_mfma_f32_16x16x32_bf16(
              vf[half][ch], pf[qs][ch], o[qs][half], 0, 0, 0);
      }
    }
  }

  // write unnormalized partials: po[part][head][d][q], lp[part][head][q]
#pragma unroll
  for (int qs = 0; qs < 2; ++qs) {
    int q = q0 + qs * 16 + c;
    if (g == 0) lp[((size_t)z * NHEAD + head) * N_TOK + q] = lf[qs][0];
#pragma unroll
    for (int half = 0; half < 2; ++half)
#pragma unroll
      for (int reg = 0; reg < 4; ++reg) {
        int d = half * 16 + g * 4 + reg;
        po[(((size_t)z * NHEAD + head) * DH + d) * N_TOK + q] = o[qs][half][reg];
      }
  }
}

// merge the 2 KV-parts: ao[q][head*32+d] = (o0+o1)/(l0+l1), via LDS transpose
__global__ __launch_bounds__(256) void attn_merge(
    const float* __restrict__ po, const float* __restrict__ lp,
    ushort_t* __restrict__ ao) {
  __shared__ ushort_t tile[DH][72];
  int qt = blockIdx.x, head = blockIdx.y;
  int t = threadIdx.x;
  int qBase = qt * 64;
  int d = t >> 3, qc = (t & 7) * 8;
  const float* o0 = po + ((size_t)(0 * NHEAD + head) * DH + d) * N_TOK + qBase + qc;
  const float* o1 = po + ((size_t)(1 * NHEAD + head) * DH + d) * N_TOK + qBase + qc;
  const float* l0 = lp + (size_t)(0 * NHEAD + head) * N_TOK + qBase + qc;
  const float* l1 = lp + (size_t)(1 * NHEAD + head) * N_TOK + qBase + qc;
#pragma unroll
  for (int j = 0; j < 8; ++j)
    tile[d][qc + j] = f2bf((o0[j] + o1[j]) / (l0[j] + l1[j]));
  __syncthreads();
  int ql = t >> 2, dc = (t & 3) * 8;
  short8 v;
#pragma unroll
  for (int j = 0; j < 8; ++j) v[j] = (short)tile[dc + j][ql];
  *(short8*)(ao + (size_t)(qBase + ql) * D + head * DH + dc) = v;
}

// ------------------------- depthwise conv + next-LN ------------------------
__global__ void scatter_kernel(const int* __restrict__ coords,
                               int* __restrict__ pos2tok) {
  int n = blockIdx.x * 256 + threadIdx.x;
  if (n < N_TOK) pos2tok[coords[2 * n] * GW + coords[2 * n + 1]] = n;
}

__global__ __launch_bounds__(256) void conv_ln_kernel(
    const float* __restrict__ xin, float* __restrict__ xout,
    const float* __restrict__ ck, const float* __restrict__ cb,
    const int* __restrict__ pos2tok, const int* __restrict__ coords,
    const float* __restrict__ g, const float* __restrict__ b,
    float* __restrict__ yf, ushort_t* __restrict__ ybf) {
  int n = blockIdx.x, t = threadIdx.x;
  __shared__ int nb[9];
  if (t < 9) {
    int r = coords[2 * n], c = coords[2 * n + 1];
    int dy = t / 3 - 1, dx = t % 3 - 1;
    int rr = r + dy, cc = c + dx;
    nb[t] = (rr >= 0 && rr < GH && cc >= 0 && cc < GW) ? pos2tok[rr * GW + cc] : -1;
  }
  __syncthreads();
  float v[2];
#pragma unroll
  for (int j = 0; j < 2; ++j) {
    int ch = t + j * 256;
    float s = cb[ch];
#pragma unroll
    for (int tap = 0; tap < 9; ++tap) {
      int tok = nb[tap];
      if (tok >= 0) s = fmaf(ck[ch * 9 + tap], xin[(size_t)tok * D + ch], s);
    }
    v[j] = xin[(size_t)n * D + ch] + s;
    xout[(size_t)n * D + ch] = v[j];
  }
  float s = v[0] + v[1];
  float sq = v[0] * v[0] + v[1] * v[1];
#pragma unroll
  for (int off = 32; off > 0; off >>= 1) {
    s += __shfl_down(s, off, 64);
    sq += __shfl_down(sq, off, 64);
  }
  __shared__ float s1[4], s2[4];
  int wid = t >> 6, lane = t & 63;
  if (lane == 0) { s1[wid] = s; s2[wid] = sq; }
  __syncthreads();
  float tot = s1[0] + s1[1] + s1[2] + s1[3];
  float totq = s2[0] + s2[1] + s2[2] + s2[3];
  float mean = tot * (1.0f / D);
  float var = totq * (1.0f / D) - mean * mean;
  float rs = rsqrtf(var + 1e-5f);
  float r0 = (v[0] - mean) * rs * g[t] + b[t];
  float r1 = (v[1] - mean) * rs * g[t + 256] + b[t + 256];
  if (yf) { yf[(size_t)n * D + t] = r0; yf[(size_t)n * D + t + 256] = r1; }
  ybf[(size_t)n * D + t] = f2bf(r0);
  ybf[(size_t)n * D + t + 256] = f2bf(r1);
}

// ------------------------ weight cast (fp32->bf16, pad) --------------------
__global__ __launch_bounds__(256) void castw(const float* __restrict__ src,
    ushort_t* __restrict__ dst, int n_src, int n_dst) {
  int i = (blockIdx.x * 256 + threadIdx.x) * 4;
  if (i >= n_dst) return;
  unsigned long long pk = 0;
#pragma unroll
  for (int j = 0; j < 4; ++j) {
    float v = (i + j < n_src) ? src[i + j] : 0.f;
    pk |= ((unsigned long long)f2bf(v)) << (16 * j);
  }
  *(unsigned long long*)(dst + i) = pk;
}

__global__ void pad_bias(const float* __restrict__ src, float* __restrict__ dst) {
  int i = threadIdx.x;
  dst[i] = (i < GENES) ? src[i] : 0.f;
}

// ------------------------------- launch ------------------------------------
extern "C" void kernel_launch(void* const* d_in, const int* in_sizes, int n_in,
                              void* d_out, int out_size, void* d_ws, size_t ws_size,
                              hipStream_t stream) {
  const float* gf     = (const float*)d_in[0];
  const int*   coords = (const int*)d_in[1];
  const float* ln1_g  = (const float*)d_in[4];
  const float* ln1_b  = (const float*)d_in[5];
  const float* wqkv   = (const float*)d_in[6];
  const float* bqkv   = (const float*)d_in[7];
  const float* wo     = (const float*)d_in[8];
  const float* bo     = (const float*)d_in[9];
  const float* ln2_g  = (const float*)d_in[10];
  const float* ln2_b  = (const float*)d_in[11];
  const float* w1     = (const float*)d_in[12];
  const float* b1     = (const float*)d_in[13];
  const float* w2     = (const float*)d_in[14];
  const float* b2     = (const float*)d_in[15];
  const float* ck     = (const float*)d_in[16];
  const float* cb     = (const float*)d_in[17];
  const float* lnf_g  = (const float*)d_in[18];
  const float* lnf_b  = (const float*)d_in[19];
  const float* wp     = (const float*)d_in[20];
  const float* bp     = (const float*)d_in[21];
  float* out = (float*)d_out;

  const size_t ND = (size_t)N_TOK * D;
  float* xb0 = (float*)d_ws;
  float* xb1 = xb0 + ND;
  ushort_t* xn_bf  = (ushort_t*)(xb1 + ND);      // ND
  ushort_t* ao_bf  = xn_bf + ND;                 // ND
  ushort_t* out_bf = ao_bf + ND;                 // ND
  ushort_t* shared = out_bf + ND;                // max(3*ND, N*MLPD)
  ushort_t* qb   = shared;
  ushort_t* kbuf = qb + ND;
  ushort_t* vtb  = kbuf + ND;
  ushort_t* h_bf = shared;                       // aliases qkv bufs (disjoint lifetime)
  ushort_t* wqkv_bf = shared + (size_t)N_TOK * MLPD;
  ushort_t* wo_bf = wqkv_bf + DEPTH * 3 * D * D;
  ushort_t* w1_bf = wo_bf + DEPTH * D * D;
  ushort_t* w2_bf = w1_bf + DEPTH * MLPD * D;
  ushort_t* wp_bf = w2_bf + DEPTH * D * MLPD;
  float* bp_pad = (float*)(wp_bf + 256 * D);
  int* pos2tok = (int*)(bp_pad + 256);
  float* po = (float*)(pos2tok + GH * GW);       // 2*NH*DH*N_TOK fp32 = 16.8 MB
  float* lp = po + (size_t)2 * NHEAD * DH * N_TOK;  // 2*NH*N_TOK fp32

  hipMemcpyAsync(xb0, gf, ND * sizeof(float), hipMemcpyDeviceToDevice, stream);
  hipMemsetAsync(pos2tok, 0xFF, GH * GW * sizeof(int), stream);
  scatter_kernel<<<(N_TOK + 255) / 256, 256, 0, stream>>>(coords, pos2tok);

  int nw;
  nw = DEPTH * 3 * D * D;  castw<<<(nw / 4 + 255) / 256, 256, 0, stream>>>(wqkv, wqkv_bf, nw, nw);
  nw = DEPTH * D * D;      castw<<<(nw / 4 + 255) / 256, 256, 0, stream>>>(wo, wo_bf, nw, nw);
  nw = DEPTH * MLPD * D;   castw<<<(nw / 4 + 255) / 256, 256, 0, stream>>>(w1, w1_bf, nw, nw);
  nw = DEPTH * D * MLPD;   castw<<<(nw / 4 + 255) / 256, 256, 0, stream>>>(w2, w2_bf, nw, nw);
  castw<<<(256 * D / 4 + 255) / 256, 256, 0, stream>>>(wp, wp_bf, GENES * D, 256 * D);
  pad_bias<<<1, 256, 0, stream>>>(bp, bp_pad);

  // ln1 of layer 0 (subsequent ln1/lnf are fused into conv_ln)
  ln_kernel<<<N_TOK, 256, 0, stream>>>(xb0, ln1_g, ln1_b, nullptr, xn_bf);

  float* x  = xb0;
  float* xo = xb1;
  for (int i = 0; i < DEPTH; ++i) {
    gemm_bf<128, 128, 1><<<dim3(12, 32), 256, 0, stream>>>(
        xn_bf, wqkv_bf + (size_t)i * 3 * D * D, bqkv + (size_t)i * 3 * D,
        nullptr, nullptr, nullptr, qb, kbuf, vtb, D, 0, 3 * D, 2);
    attn_mfma<<<dim3(N_TOK / 128, NHEAD, 2), 256, 0, stream>>>(qb, kbuf, vtb, po, lp);
    attn_merge<<<dim3(N_TOK / 64, NHEAD), 256, 0, stream>>>(po, lp, ao_bf);
    gemm_bf<64, 64, 2><<<dim3(8, 64), 256, 0, stream>>>(
        ao_bf, wo_bf + (size_t)i * D * D, bo + (size_t)i * D,
        x, x, nullptr, nullptr, nullptr, nullptr, D, D, D, 0);
    ln_kernel<<<N_TOK, 256, 0, stream>>>(x, ln2_g + i * D, ln2_b + i * D, nullptr, xn_bf);
    gemm_bf<128, 128, 1><<<dim3(16, 32), 256, 0, stream>>>(
        xn_bf, w1_bf + (size_t)i * MLPD * D, b1 + (size_t)i * MLPD,
        nullptr, nullptr, h_bf, nullptr, nullptr, nullptr, D, MLPD, MLPD, 1);
    gemm_bf<64, 64, 2><<<dim3(8, 64), 256, 0, stream>>>(
        h_bf, w2_bf + (size_t)i * D * MLPD, b2 + (size_t)i * D,
        x, x, nullptr, nullptr, nullptr, nullptr, MLPD, D, D, 0);
    if (i < DEPTH - 1) {
      conv_ln_kernel<<<N_TOK, 256, 0, stream>>>(
          x, xo, ck + (size_t)i * D * 9, cb + (size_t)i * D, pos2tok, coords,
          ln1_g + (i + 1) * D, ln1_b + (i + 1) * D, nullptr, xn_bf);
    } else {
      conv_ln_kernel<<<N_TOK, 256, 0, stream>>>(
          x, xo, ck + (size_t)i * D * 9, cb + (size_t)i * D, pos2tok, coords,
          lnf_g, lnf_b, out, out_bf);
    }
    float* tmp = x; x = xo; xo = tmp;
  }
  gemm_bf<64, 64, 2><<<dim3(4, 64), 256, 0, stream>>>(
      out_bf, wp_bf, bp_pad, nullptr, out + ND, nullptr, nullptr, nullptr, nullptr,
      D, GENES, GENES, 0);
}

// Round 10
// 621.622 us; speedup vs baseline: 1.1287x; 1.0187x over previous
//
#include <hip/hip_runtime.h>
#include <math.h>

#define D 512
#define N_TOK 4096
#define NHEAD 16
#define DH 32
#define DEPTH 3
#define MLPD 2048
#define GENES 250
#define GH 64
#define GW 64

typedef __attribute__((ext_vector_type(8))) short short8;
typedef __attribute__((ext_vector_type(4))) float f32x4;
typedef unsigned short ushort_t;

#define AS1 __attribute__((address_space(1)))
#define AS3 __attribute__((address_space(3)))

#if defined(__has_builtin)
#if __has_builtin(__builtin_amdgcn_exp2f)
#define EXP2F(x) __builtin_amdgcn_exp2f(x)
#endif
#endif
#ifndef EXP2F
#define EXP2F(x) __expf(0.69314718056f * (x))
#endif

__device__ __forceinline__ unsigned short f2bf(float f) {
  unsigned int u = __float_as_uint(f);
  u += 0x7fffu + ((u >> 16) & 1u);
  return (unsigned short)(u >> 16);
}
__device__ __forceinline__ unsigned int bfpack(float a, float b) {
  return __builtin_amdgcn_perm(__float_as_uint(b), __float_as_uint(a), 0x07060302u);
}
__device__ __forceinline__ void gload_lds16(const ushort_t* g, ushort_t* l) {
  __builtin_amdgcn_global_load_lds(
      (const AS1 unsigned int*)g,
      (AS3 unsigned int*)(unsigned int)(unsigned long long)l, 16, 0, 0);
}
// key permutation shared by the V^T store and the attention P-fragment
__device__ __forceinline__ int perm64(int m) {
  int mi = m >> 4, g = (m >> 2) & 3, r = m & 3;
  return ((mi & 1) << 5) | (g << 3) | ((mi >> 1) << 2) | r;
}

// ------------------------------- LayerNorm --------------------------------
__global__ __launch_bounds__(256) void ln_kernel(const float* __restrict__ x,
    const float* __restrict__ g, const float* __restrict__ b,
    float* __restrict__ yf, ushort_t* __restrict__ ybf) {
  int row = blockIdx.x;
  int t = threadIdx.x;
  const float* xr = x + (size_t)row * D;
  float v0 = xr[t], v1 = xr[t + 256];
  float s = v0 + v1;
  float sq = v0 * v0 + v1 * v1;
#pragma unroll
  for (int off = 32; off > 0; off >>= 1) {
    s += __shfl_down(s, off, 64);
    sq += __shfl_down(sq, off, 64);
  }
  __shared__ float s1[4], s2[4];
  int wid = t >> 6, lane = t & 63;
  if (lane == 0) { s1[wid] = s; s2[wid] = sq; }
  __syncthreads();
  float tot = s1[0] + s1[1] + s1[2] + s1[3];
  float totq = s2[0] + s2[1] + s2[2] + s2[3];
  float mean = tot * (1.0f / D);
  float var = totq * (1.0f / D) - mean * mean;
  float rs = rsqrtf(var + 1e-5f);
  float r0 = (v0 - mean) * rs * g[t] + b[t];
  float r1 = (v1 - mean) * rs * g[t + 256] + b[t + 256];
  if (yf) { yf[(size_t)row * D + t] = r0; yf[(size_t)row * D + t + 256] = r1; }
  if (ybf) {
    ybf[(size_t)row * D + t] = f2bf(r0);
    ybf[(size_t)row * D + t + 256] = f2bf(r1);
  }
}

// ---------------------------- bf16 MFMA GEMM -------------------------------
// R7 structure (best measured): tile TMxTN, BK=32*NKH, double-buffered LDS,
// prefetch of iter k+1 issued right after the barrier releasing the buffer,
// before iter k's compute. One __syncthreads per iter.
// Fat GEMMs (QKV, MLP1) use TM=128,TN=64 -> 768/1024 blocks = 3-4 blocks/CU
// for latency overlap (R9 finding: blocks/CU is the knob this structure has).
// mode 0: fp32 C (+res). mode 1: gelu -> Cbf. mode 2: qkv routing.
template <int TM, int TN, int NKH>
__global__ __launch_bounds__(256) void gemm_bf(
    const ushort_t* __restrict__ A, const ushort_t* __restrict__ B,
    const float* __restrict__ bias, const float* __restrict__ res,
    float* __restrict__ C, ushort_t* __restrict__ Cbf,
    ushort_t* __restrict__ qO, ushort_t* __restrict__ kO, ushort_t* __restrict__ vO,
    int K, int ldc, int nstore, int mode) {
  constexpr int MI = TM / 32;
  constexpr int NI = TN / 32;
  __shared__ ushort_t As[2][NKH][TM * 32];
  __shared__ ushort_t Bs[2][NKH][TN * 32];
  int t = threadIdx.x;
  int w = t >> 6, lane = t & 63;
  int g = lane >> 4, c = lane & 15;
  int bm = blockIdx.y * TM, bn = blockIdx.x * TN;
  int wr = (w >> 1) * (TM / 2);
  int wc = (w & 1) * (TN / 2);

  const ushort_t* gA = A + (size_t)(bm + (t >> 2)) * K + (t & 3) * 8;
  const ushort_t* gB = B + (size_t)(bn + (t >> 2)) * K + (t & 3) * 8;

  auto stage = [&](int p, int koff) {
#pragma unroll
    for (int h = 0; h < NKH; ++h) {
      gload_lds16(gA + koff + h * 32, &As[p][h][t * 8]);
      if (TM == 128)
        gload_lds16(gA + koff + h * 32 + (size_t)64 * K, &As[p][h][(t + 256) * 8]);
      gload_lds16(gB + koff + h * 32, &Bs[p][h][t * 8]);
      if (TN == 128)
        gload_lds16(gB + koff + h * 32 + (size_t)64 * K, &Bs[p][h][(t + 256) * 8]);
    }
  };

  f32x4 acc[MI][NI] = {};

  const int niter = K / (32 * NKH);
  stage(0, 0);
  __syncthreads();
  for (int it = 0; it < niter; ++it) {
    int p = it & 1;
    if (it + 1 < niter) stage(p ^ 1, (it + 1) * 32 * NKH);  // prefetch overlaps compute
#pragma unroll
    for (int kh = 0; kh < NKH; ++kh) {
      short8 af[MI], bfr[NI];
#pragma unroll
      for (int mi = 0; mi < MI; ++mi)
        af[mi] = *(const short8*)&As[p][kh][(wr + mi * 16 + c) * 32 + g * 8];
#pragma unroll
      for (int ni = 0; ni < NI; ++ni)
        bfr[ni] = *(const short8*)&Bs[p][kh][(wc + ni * 16 + c) * 32 + g * 8];
#pragma unroll
      for (int mi = 0; mi < MI; ++mi)
#pragma unroll
        for (int ni = 0; ni < NI; ++ni)
          acc[mi][ni] = __builtin_amdgcn_mfma_f32_16x16x32_bf16(
              af[mi], bfr[ni], acc[mi][ni], 0, 0, 0);
    }
    __syncthreads();
  }

  const float qs_scale = 0.17677669529663688f * 1.4426950408889634f;
  if (mode == 2) {
#pragma unroll
    for (int ni = 0; ni < NI; ++ni) {
      int col = bn + wc + ni * 16 + c;
      float bv = bias[col];
      int which = col >> 9;
      int h = (col >> 5) & 15;
      int d = col & 31;
      size_t hb = (size_t)h * (N_TOK * DH);
#pragma unroll
      for (int mi = 0; mi < MI; ++mi) {
        int row0 = bm + wr + mi * 16 + g * 4;
        float v0 = acc[mi][ni][0] + bv;
        float v1 = acc[mi][ni][1] + bv;
        float v2 = acc[mi][ni][2] + bv;
        float v3 = acc[mi][ni][3] + bv;
        if (which == 0) {
          qO[hb + (size_t)(row0 + 0) * DH + d] = f2bf(v0 * qs_scale);
          qO[hb + (size_t)(row0 + 1) * DH + d] = f2bf(v1 * qs_scale);
          qO[hb + (size_t)(row0 + 2) * DH + d] = f2bf(v2 * qs_scale);
          qO[hb + (size_t)(row0 + 3) * DH + d] = f2bf(v3 * qs_scale);
        } else if (which == 1) {
          kO[hb + (size_t)(row0 + 0) * DH + d] = f2bf(v0);
          kO[hb + (size_t)(row0 + 1) * DH + d] = f2bf(v1);
          kO[hb + (size_t)(row0 + 2) * DH + d] = f2bf(v2);
          kO[hb + (size_t)(row0 + 3) * DH + d] = f2bf(v3);
        } else {
          int m = row0 & 63;
          int mi_l = m >> 4, g_l = (m >> 2) & 3;
          int nb = ((mi_l & 1) << 5) | (g_l << 3) | ((mi_l >> 1) << 2);
          uint2 pk;
          pk.x = (unsigned)f2bf(v0) | ((unsigned)f2bf(v1) << 16);
          pk.y = (unsigned)f2bf(v2) | ((unsigned)f2bf(v3) << 16);
          *(uint2*)(vO + hb + (size_t)d * N_TOK + (row0 & ~63) + nb) = pk;
        }
      }
    }
    return;
  }
#pragma unroll
  for (int ni = 0; ni < NI; ++ni) {
    int col = bn + wc + ni * 16 + c;
    float bv = bias[col];
    bool cok = col < nstore;
#pragma unroll
    for (int mi = 0; mi < MI; ++mi) {
      int row0 = bm + wr + mi * 16 + g * 4;
#pragma unroll
      for (int reg = 0; reg < 4; ++reg) {
        int row = row0 + reg;
        float v = acc[mi][ni][reg] + bv;
        if (mode == 0) {
          size_t idx = (size_t)row * ldc + col;
          if (cok) {
            if (res) v += res[idx];
            C[idx] = v;
          }
        } else {
          v = 0.5f * v * (1.0f + erff(v * 0.70710678118654752f));
          Cbf[(size_t)row * ldc + col] = f2bf(v);
        }
      }
    }
  }
}

// --------------------------- MFMA flash attention --------------------------
// R7 version verbatim (empirical plateau ~62 us/layer; R8 dbuf and R9
// KV-split both neutral-to-negative). grid (N_TOK/128, NHEAD), 256 thr.
// Single-buffer LDS staging + reg prefetch; P in registers (S^T C-frag ==
// B-frag under perm64); l on the MFMA pipe via ones-MFMA.
#define KST 40   // Ks row stride (ushorts)
#define VTST 72  // Vts row stride (ushorts)

__global__ __launch_bounds__(256) void attn_mfma(
    const ushort_t* __restrict__ qb, const ushort_t* __restrict__ kb,
    const ushort_t* __restrict__ vtb, ushort_t* __restrict__ ao) {
  __shared__ ushort_t Ks[64 * KST];
  __shared__ ushort_t Vts[32 * VTST];
  int qt = blockIdx.x, head = blockIdx.y;
  int t = threadIdx.x;
  int w = t >> 6, lane = t & 63;
  int g = lane >> 4, c = lane & 15;
  const size_t hbase = (size_t)head * (N_TOK * DH);
  int q0 = qt * 128 + w * 32;

  short8 qf[2];
  qf[0] = *(const short8*)(qb + hbase + (size_t)(q0 + c) * DH + g * 8);
  qf[1] = *(const short8*)(qb + hbase + (size_t)(q0 + 16 + c) * DH + g * 8);

  short8 ones;
#pragma unroll
  for (int i = 0; i < 8; ++i) ones[i] = (short)0x3F80;

  f32x4 o[2][2] = {};
  f32x4 lf[2] = {};
  const f32x4 zf = {0.f, 0.f, 0.f, 0.f};

  const ushort_t* kg = kb + hbase + (size_t)(t >> 2) * DH + (t & 3) * 8;
  const ushort_t* vg = vtb + hbase + (size_t)(t >> 3) * N_TOK + (t & 7) * 8;
  ushort_t* kw = &Ks[(t >> 2) * KST + (t & 3) * 8];
  ushort_t* vw = &Vts[(t >> 3) * VTST + (t & 7) * 8];

  short8 kreg = *(const short8*)kg;
  short8 vreg = *(const short8*)vg;

  typedef union { short8 s8; unsigned int u32[4]; } pk_t;

  for (int tile = 0; tile < N_TOK / 64; ++tile) {
    __syncthreads();
    *(short8*)kw = kreg;
    *(short8*)vw = vreg;
    __syncthreads();
    if (tile + 1 < N_TOK / 64) {
      kreg = *(const short8*)(kg + (size_t)(tile + 1) * 64 * DH);
      vreg = *(const short8*)(vg + (tile + 1) * 64);
    }

    short8 kf[4];
#pragma unroll
    for (int mi = 0; mi < 4; ++mi)
      kf[mi] = *(const short8*)&Ks[(mi * 16 + c) * KST + g * 8];
    short8 vf[2][2];
#pragma unroll
    for (int half = 0; half < 2; ++half)
#pragma unroll
      for (int ch = 0; ch < 2; ++ch)
        vf[half][ch] = *(const short8*)&Vts[(half * 16 + c) * VTST + ch * 32 + g * 8];

    short8 pf[2][2];
#pragma unroll
    for (int qs = 0; qs < 2; ++qs) {
      f32x4 sp[4];
#pragma unroll
      for (int mi = 0; mi < 4; ++mi)
        sp[mi] = __builtin_amdgcn_mfma_f32_16x16x32_bf16(kf[mi], qf[qs], zf, 0, 0, 0);
      float pr[4][4];
#pragma unroll
      for (int mi = 0; mi < 4; ++mi)
#pragma unroll
        for (int r = 0; r < 4; ++r) pr[mi][r] = EXP2F(sp[mi][r]);
      pk_t p0, p1;
      p0.u32[0] = bfpack(pr[0][0], pr[0][1]);
      p0.u32[1] = bfpack(pr[0][2], pr[0][3]);
      p0.u32[2] = bfpack(pr[2][0], pr[2][1]);
      p0.u32[3] = bfpack(pr[2][2], pr[2][3]);
      p1.u32[0] = bfpack(pr[1][0], pr[1][1]);
      p1.u32[1] = bfpack(pr[1][2], pr[1][3]);
      p1.u32[2] = bfpack(pr[3][0], pr[3][1]);
      p1.u32[3] = bfpack(pr[3][2], pr[3][3]);
      pf[qs][0] = p0.s8;
      pf[qs][1] = p1.s8;
    }

#pragma unroll
    for (int qs = 0; qs < 2; ++qs) {
#pragma unroll
      for (int ch = 0; ch < 2; ++ch) {
        lf[qs] = __builtin_amdgcn_mfma_f32_16x16x32_bf16(ones, pf[qs][ch], lf[qs], 0, 0, 0);
#pragma unroll
        for (int half = 0; half < 2; ++half)
          o[qs][half] = __builtin_amdgcn_mfma_f32_16x16x32_bf16(
              vf[half][ch], pf[qs][ch], o[qs][half], 0, 0, 0);
      }
    }
  }

#pragma unroll
  for (int qs = 0; qs < 2; ++qs) {
    float inv = 1.0f / lf[qs][0];
    int q = q0 + qs * 16 + c;
    ushort_t* op = ao + (size_t)q * D + head * DH;
#pragma unroll
    for (int half = 0; half < 2; ++half)
#pragma unroll
      for (int reg = 0; reg < 4; ++reg)
        op[half * 16 + g * 4 + reg] = f2bf(o[qs][half][reg] * inv);
  }
}

// ------------------------- depthwise conv + next-LN ------------------------
__global__ void scatter_kernel(const int* __restrict__ coords,
                               int* __restrict__ pos2tok) {
  int n = blockIdx.x * 256 + threadIdx.x;
  if (n < N_TOK) pos2tok[coords[2 * n] * GW + coords[2 * n + 1]] = n;
}

__global__ __launch_bounds__(256) void conv_ln_kernel(
    const float* __restrict__ xin, float* __restrict__ xout,
    const float* __restrict__ ck, const float* __restrict__ cb,
    const int* __restrict__ pos2tok, const int* __restrict__ coords,
    const float* __restrict__ g, const float* __restrict__ b,
    float* __restrict__ yf, ushort_t* __restrict__ ybf) {
  int n = blockIdx.x, t = threadIdx.x;
  __shared__ int nb[9];
  if (t < 9) {
    int r = coords[2 * n], c = coords[2 * n + 1];
    int dy = t / 3 - 1, dx = t % 3 - 1;
    int rr = r + dy, cc = c + dx;
    nb[t] = (rr >= 0 && rr < GH && cc >= 0 && cc < GW) ? pos2tok[rr * GW + cc] : -1;
  }
  __syncthreads();
  float v[2];
#pragma unroll
  for (int j = 0; j < 2; ++j) {
    int ch = t + j * 256;
    float s = cb[ch];
#pragma unroll
    for (int tap = 0; tap < 9; ++tap) {
      int tok = nb[tap];
      if (tok >= 0) s = fmaf(ck[ch * 9 + tap], xin[(size_t)tok * D + ch], s);
    }
    v[j] = xin[(size_t)n * D + ch] + s;
    xout[(size_t)n * D + ch] = v[j];
  }
  float s = v[0] + v[1];
  float sq = v[0] * v[0] + v[1] * v[1];
#pragma unroll
  for (int off = 32; off > 0; off >>= 1) {
    s += __shfl_down(s, off, 64);
    sq += __shfl_down(sq, off, 64);
  }
  __shared__ float s1[4], s2[4];
  int wid = t >> 6, lane = t & 63;
  if (lane == 0) { s1[wid] = s; s2[wid] = sq; }
  __syncthreads();
  float tot = s1[0] + s1[1] + s1[2] + s1[3];
  float totq = s2[0] + s2[1] + s2[2] + s2[3];
  float mean = tot * (1.0f / D);
  float var = totq * (1.0f / D) - mean * mean;
  float rs = rsqrtf(var + 1e-5f);
  float r0 = (v[0] - mean) * rs * g[t] + b[t];
  float r1 = (v[1] - mean) * rs * g[t + 256] + b[t + 256];
  if (yf) { yf[(size_t)n * D + t] = r0; yf[(size_t)n * D + t + 256] = r1; }
  ybf[(size_t)n * D + t] = f2bf(r0);
  ybf[(size_t)n * D + t + 256] = f2bf(r1);
}

// ------------------------ weight cast (fp32->bf16, pad) --------------------
__global__ __launch_bounds__(256) void castw(const float* __restrict__ src,
    ushort_t* __restrict__ dst, int n_src, int n_dst) {
  int i = (blockIdx.x * 256 + threadIdx.x) * 4;
  if (i >= n_dst) return;
  unsigned long long pk = 0;
#pragma unroll
  for (int j = 0; j < 4; ++j) {
    float v = (i + j < n_src) ? src[i + j] : 0.f;
    pk |= ((unsigned long long)f2bf(v)) << (16 * j);
  }
  *(unsigned long long*)(dst + i) = pk;
}

__global__ void pad_bias(const float* __restrict__ src, float* __restrict__ dst) {
  int i = threadIdx.x;
  dst[i] = (i < GENES) ? src[i] : 0.f;
}

// ------------------------------- launch ------------------------------------
extern "C" void kernel_launch(void* const* d_in, const int* in_sizes, int n_in,
                              void* d_out, int out_size, void* d_ws, size_t ws_size,
                              hipStream_t stream) {
  const float* gf     = (const float*)d_in[0];
  const int*   coords = (const int*)d_in[1];
  const float* ln1_g  = (const float*)d_in[4];
  const float* ln1_b  = (const float*)d_in[5];
  const float* wqkv   = (const float*)d_in[6];
  const float* bqkv   = (const float*)d_in[7];
  const float* wo     = (const float*)d_in[8];
  const float* bo     = (const float*)d_in[9];
  const float* ln2_g  = (const float*)d_in[10];
  const float* ln2_b  = (const float*)d_in[11];
  const float* w1     = (const float*)d_in[12];
  const float* b1     = (const float*)d_in[13];
  const float* w2     = (const float*)d_in[14];
  const float* b2     = (const float*)d_in[15];
  const float* ck     = (const float*)d_in[16];
  const float* cb     = (const float*)d_in[17];
  const float* lnf_g  = (const float*)d_in[18];
  const float* lnf_b  = (const float*)d_in[19];
  const float* wp     = (const float*)d_in[20];
  const float* bp     = (const float*)d_in[21];
  float* out = (float*)d_out;

  const size_t ND = (size_t)N_TOK * D;
  float* xb0 = (float*)d_ws;
  float* xb1 = xb0 + ND;
  ushort_t* xn_bf  = (ushort_t*)(xb1 + ND);      // ND
  ushort_t* ao_bf  = xn_bf + ND;                 // ND
  ushort_t* out_bf = ao_bf + ND;                 // ND
  ushort_t* shared = out_bf + ND;                // max(3*ND, N*MLPD)
  ushort_t* qb   = shared;
  ushort_t* kbuf = qb + ND;
  ushort_t* vtb  = kbuf + ND;
  ushort_t* h_bf = shared;                       // aliases qkv bufs (disjoint lifetime)
  ushort_t* wqkv_bf = shared + (size_t)N_TOK * MLPD;
  ushort_t* wo_bf = wqkv_bf + DEPTH * 3 * D * D;
  ushort_t* w1_bf = wo_bf + DEPTH * D * D;
  ushort_t* w2_bf = w1_bf + DEPTH * MLPD * D;
  ushort_t* wp_bf = w2_bf + DEPTH * D * MLPD;
  float* bp_pad = (float*)(wp_bf + 256 * D);
  int* pos2tok = (int*)(bp_pad + 256);

  hipMemcpyAsync(xb0, gf, ND * sizeof(float), hipMemcpyDeviceToDevice, stream);
  hipMemsetAsync(pos2tok, 0xFF, GH * GW * sizeof(int), stream);
  scatter_kernel<<<(N_TOK + 255) / 256, 256, 0, stream>>>(coords, pos2tok);

  int nw;
  nw = DEPTH * 3 * D * D;  castw<<<(nw / 4 + 255) / 256, 256, 0, stream>>>(wqkv, wqkv_bf, nw, nw);
  nw = DEPTH * D * D;      castw<<<(nw / 4 + 255) / 256, 256, 0, stream>>>(wo, wo_bf, nw, nw);
  nw = DEPTH * MLPD * D;   castw<<<(nw / 4 + 255) / 256, 256, 0, stream>>>(w1, w1_bf, nw, nw);
  nw = DEPTH * D * MLPD;   castw<<<(nw / 4 + 255) / 256, 256, 0, stream>>>(w2, w2_bf, nw, nw);
  castw<<<(256 * D / 4 + 255) / 256, 256, 0, stream>>>(wp, wp_bf, GENES * D, 256 * D);
  pad_bias<<<1, 256, 0, stream>>>(bp, bp_pad);

  // ln1 of layer 0 (subsequent ln1/lnf are fused into conv_ln)
  ln_kernel<<<N_TOK, 256, 0, stream>>>(xb0, ln1_g, ln1_b, nullptr, xn_bf);

  float* x  = xb0;
  float* xo = xb1;
  for (int i = 0; i < DEPTH; ++i) {
    // QKV: 128x64 tile -> 768 blocks = 3 blocks/CU
    gemm_bf<128, 64, 1><<<dim3(24, 32), 256, 0, stream>>>(
        xn_bf, wqkv_bf + (size_t)i * 3 * D * D, bqkv + (size_t)i * 3 * D,
        nullptr, nullptr, nullptr, qb, kbuf, vtb, D, 0, 3 * D, 2);
    attn_mfma<<<dim3(N_TOK / 128, NHEAD), 256, 0, stream>>>(qb, kbuf, vtb, ao_bf);
    gemm_bf<64, 64, 2><<<dim3(8, 64), 256, 0, stream>>>(
        ao_bf, wo_bf + (size_t)i * D * D, bo + (size_t)i * D,
        x, x, nullptr, nullptr, nullptr, nullptr, D, D, D, 0);
    ln_kernel<<<N_TOK, 256, 0, stream>>>(x, ln2_g + i * D, ln2_b + i * D, nullptr, xn_bf);
    // MLP1: 128x64 tile -> 1024 blocks = 4 blocks/CU
    gemm_bf<128, 64, 1><<<dim3(32, 32), 256, 0, stream>>>(
        xn_bf, w1_bf + (size_t)i * MLPD * D, b1 + (size_t)i * MLPD,
        nullptr, nullptr, h_bf, nullptr, nullptr, nullptr, D, MLPD, MLPD, 1);
    gemm_bf<64, 64, 2><<<dim3(8, 64), 256, 0, stream>>>(
        h_bf, w2_bf + (size_t)i * D * MLPD, b2 + (size_t)i * D,
        x, x, nullptr, nullptr, nullptr, nullptr, MLPD, D, D, 0);
    if (i < DEPTH - 1) {
      conv_ln_kernel<<<N_TOK, 256, 0, stream>>>(
          x, xo, ck + (size_t)i * D * 9, cb + (size_t)i * D, pos2tok, coords,
          ln1_g + (i + 1) * D, ln1_b + (i + 1) * D, nullptr, xn_bf);
    } else {
      conv_ln_kernel<<<N_TOK, 256, 0, stream>>>(
          x, xo, ck + (size_t)i * D * 9, cb + (size_t)i * D, pos2tok, coords,
          lnf_g, lnf_b, out, out_bf);
    }
    float* tmp = x; x = xo; xo = tmp;
  }
  gemm_bf<64, 64, 2><<<dim3(4, 64), 256, 0, stream>>>(
      out_bf, wp_bf, bp_pad, nullptr, out + ND, nullptr, nullptr, nullptr, nullptr,
      D, GENES, GENES, 0);
}